// Round 5
// baseline (490.296 us; speedup 1.0000x reference)
//
#include <hip/hip_runtime.h>
#include <hip/hip_bf16.h>

namespace {

constexpr int Bsz = 4, S = 2048, H = 1024, HH = 16, DH = 64;
constexpr int M = Bsz * S;      // 8192 rows
constexpr int NQKV = 3 * H;     // 3072
constexpr float SCALE = 0.125f; // Dh^-0.5
// -ln(10000)/32  (inv_freq = exp(d * this))
constexpr float NEG_LOG_BASE_OVER_HALF = -0.2878231366242557f;

typedef float f32x4 __attribute__((ext_vector_type(4)));
typedef short short8_t __attribute__((ext_vector_type(8)));
typedef short short4_t __attribute__((ext_vector_type(4)));

__device__ __forceinline__ void glds16(const void* g, void* l) {
  __builtin_amdgcn_global_load_lds(
      (const __attribute__((address_space(1))) void*)g,
      (__attribute__((address_space(3))) void*)l, 16, 0, 0);
}

__device__ __forceinline__ short f2bf(float f) {
  __hip_bfloat16 h = __float2bfloat16(f);
  return *reinterpret_cast<short*>(&h);
}

// ---------------- conversion kernels ----------------
__global__ void cvt_f32_bf16(const float* __restrict__ src, short* __restrict__ dst, int n4) {
  int i = blockIdx.x * blockDim.x + threadIdx.x;
  const int stride = gridDim.x * blockDim.x;
  const float4* s4 = reinterpret_cast<const float4*>(src);
  short4_t* d4 = reinterpret_cast<short4_t*>(dst);
  for (; i < n4; i += stride) {
    float4 f = s4[i];
    short4_t o;
    o.x = f2bf(f.x); o.y = f2bf(f.y); o.z = f2bf(f.z); o.w = f2bf(f.w);
    d4[i] = o;
  }
}

// dst[c][r] = bf16(src[r][c]); R,C multiples of 32.
__global__ void tconv(const float* __restrict__ src, short* __restrict__ dst, int R, int C) {
  __shared__ float t[32][33];
  const int c0 = blockIdx.x * 32, r0 = blockIdx.y * 32;
  for (int i = threadIdx.y; i < 32; i += 8)
    t[i][threadIdx.x] = src[(r0 + i) * C + c0 + threadIdx.x];
  __syncthreads();
  for (int i = threadIdx.y; i < 32; i += 8)
    dst[(c0 + i) * R + r0 + threadIdx.x] = f2bf(t[threadIdx.x][i]);
}

// RoPE table: ctab/stab[s*32+d] = cos/sin(positions[s] * base^(-d/32)).
// m205 lesson: on-device large-arg sinf/cosf in the GEMM epilogue is VALU-bound;
// 512 KB table is L2-resident and amortized over the whole QKV GEMM.
__global__ void rope_tab(const int* __restrict__ positions, float* __restrict__ ctab,
                         float* __restrict__ stab) {
  const int i = blockIdx.x * blockDim.x + threadIdx.x;  // [0, S*32)
  const int s = i >> 5, d = i & 31;
  const float ang = (float)positions[s] * expf((float)d * NEG_LOG_BASE_OVER_HALF);
  ctab[i] = cosf(ang);
  stab[i] = sinf(ang);
}

// ---------------- QKV GEMM + bias + RoPE ----------------
// X: [8192][1024] bf16, Wt: [3072][1024] bf16 (transposed), out q/k/v: [b][h][s][64] bf16
__global__ __launch_bounds__(256, 2)
void gemm_qkv(const short* __restrict__ X, const short* __restrict__ Wt,
              const float* __restrict__ bias, const float* __restrict__ ctab,
              const float* __restrict__ stab,
              short* __restrict__ Qo, short* __restrict__ Ko, short* __restrict__ Vo) {
  __shared__ __align__(16) short As[128 * 32];
  __shared__ __align__(16) short Bs[128 * 32];
  const int tid = threadIdx.x, lane = tid & 63, wid = tid >> 6;
  const int l15 = lane & 15, hi = lane >> 4;
  const int m0 = blockIdx.x * 128, n0 = blockIdx.y * 128;
  const int wr = wid >> 1, wc = wid & 1;
  f32x4 acc[4][4];
#pragma unroll
  for (int m = 0; m < 4; ++m)
#pragma unroll
    for (int n = 0; n < 4; ++n) acc[m][n] = (f32x4){0.f, 0.f, 0.f, 0.f};

  for (int kt = 0; kt < 32; ++kt) {
    const int k0 = kt * 32;
    __syncthreads();
#pragma unroll
    for (int j = 0; j < 2; ++j) {
      const int c = j * 256 + wid * 64 + lane;
      glds16(X + (m0 + (c >> 2)) * 1024 + k0 + (c & 3) * 8,
             (char*)As + (j * 256 + wid * 64) * 16);
      glds16(Wt + (n0 + (c >> 2)) * 1024 + k0 + (c & 3) * 8,
             (char*)Bs + (j * 256 + wid * 64) * 16);
    }
    __syncthreads();
    short8_t a[4], b[4];
#pragma unroll
    for (int m = 0; m < 4; ++m)
      a[m] = *(const short8_t*)&As[(wr * 64 + m * 16 + l15) * 32 + hi * 8];
#pragma unroll
    for (int n = 0; n < 4; ++n)
      b[n] = *(const short8_t*)&Bs[(wc * 64 + n * 16 + l15) * 32 + hi * 8];
#pragma unroll
    for (int m = 0; m < 4; ++m)
#pragma unroll
      for (int n = 0; n < 4; ++n)
        acc[m][n] = __builtin_amdgcn_mfma_f32_16x16x32_bf16(a[m], b[n], acc[m][n], 0, 0, 0);
  }

  // Epilogue. Wave's 64-col span = one head of one section (q/k/v).
  const int colbase = n0 + wc * 64;
  const int sec = colbase >> 10;          // 0=q 1=k 2=v
  const int hh = (colbase & 1023) >> 6;   // head
  short* const outp = (sec == 0) ? Qo : (sec == 1) ? Ko : Vo;
  if (sec == 2) {
#pragma unroll
    for (int m = 0; m < 4; ++m)
#pragma unroll
      for (int r = 0; r < 4; ++r) {
        const int grow = m0 + wr * 64 + m * 16 + hi * 4 + r;
        const int b = grow >> 11, s = grow & 2047;
        const int base = ((b * HH + hh) * S + s) * DH;
#pragma unroll
        for (int n = 0; n < 4; ++n) {
          const int d = n * 16 + l15;
          outp[base + d] = f2bf(acc[m][n][r] + bias[colbase + d]);
        }
      }
  } else {
#pragma unroll
    for (int m = 0; m < 4; ++m)
#pragma unroll
      for (int r = 0; r < 4; ++r) {
        const int grow = m0 + wr * 64 + m * 16 + hi * 4 + r;
        const int b = grow >> 11, s = grow & 2047;
        const int base = ((b * HH + hh) * S + s) * DH;
#pragma unroll
        for (int n = 0; n < 2; ++n) {  // pair (n, n+2): d and d+32, same lane
          const int d1 = n * 16 + l15;
          const float x1 = acc[m][n][r] + bias[colbase + d1];
          const float x2 = acc[m][n + 2][r] + bias[colbase + d1 + 32];
          const float cs = ctab[s * 32 + d1], sn = stab[s * 32 + d1];
          outp[base + d1] = f2bf(x1 * cs - x2 * sn);
          outp[base + d1 + 32] = f2bf(x2 * cs + x1 * sn);
        }
      }
  }
}

// ---------------- flash attention ----------------
// Q/K/V: [bh][s][64] bf16. ctx out: [b][s][h*64+d] bf16. One block: 64 q-rows, 4 waves x 16 rows.
__global__ __launch_bounds__(256, 2)
void attn(const short* __restrict__ Q, const short* __restrict__ K,
          const short* __restrict__ V, short* __restrict__ ctx) {
  __shared__ __align__(16) short Kl[64 * 64];   // [s][d], XOR-swizzled rows
  __shared__ __align__(16) short Vt[64 * 64];   // [d][s], XOR-swizzled rows
  __shared__ __align__(16) short Pf[4 * 1024];  // per-wave P in A-frag layout
  const int tid = threadIdx.x, lane = tid & 63, wid = tid >> 6;
  const int l15 = lane & 15, hi = lane >> 4;
  const int bh = blockIdx.y;
  const int q0 = blockIdx.x * 64;
  const short* Qb = Q + bh * (S * DH);
  const short* Kb = K + bh * (S * DH);
  const short* Vb = V + bh * (S * DH);

  const int qrow = q0 + wid * 16 + l15;
  short8_t qf[2];
  qf[0] = *(const short8_t*)&Qb[qrow * 64 + hi * 8];
  qf[1] = *(const short8_t*)&Qb[qrow * 64 + 32 + hi * 8];

  f32x4 o[4];
  float mrun[4], lrun[4];
#pragma unroll
  for (int i = 0; i < 4; ++i) { o[i] = (f32x4){0.f, 0.f, 0.f, 0.f}; mrun[i] = -1e30f; lrun[i] = 0.f; }

  for (int kt = 0; kt < 32; ++kt) {
    __syncthreads();
    // stage K: global_load_lds, swizzle folded into the *global* source address (m173)
#pragma unroll
    for (int j = 0; j < 2; ++j) {
      const int c = j * 256 + wid * 64 + lane;
      const int srow = c >> 3;
      glds16((const char*)(Kb + (kt * 64 + srow) * 64) + (((c & 7) * 16) ^ ((srow & 7) << 4)),
             (char*)Kl + (j * 256 + wid * 64) * 16);
    }
    // stage V transposed (+swizzle): coalesced 16B global reads, scalar LDS writes
#pragma unroll
    for (int j = 0; j < 2; ++j) {
      const int c = j * 256 + tid;
      const int sv = c >> 3, d0 = (c & 7) * 8;
      short8_t vv = *(const short8_t*)&Vb[(kt * 64 + sv) * 64 + d0];
#pragma unroll
      for (int e = 0; e < 8; ++e) {
        const int d = d0 + e;
        *(short*)((char*)Vt + d * 128 + ((sv * 2) ^ ((d & 7) << 4))) = vv[e];
      }
    }
    __syncthreads();

    // QK^T: scores 16(q) x 64(k) per wave
    f32x4 s4[4];
#pragma unroll
    for (int nf = 0; nf < 4; ++nf) {
      s4[nf] = (f32x4){0.f, 0.f, 0.f, 0.f};
      const int scol = nf * 16 + l15;
#pragma unroll
      for (int st = 0; st < 2; ++st) {
        short8_t kf = *(const short8_t*)((const char*)Kl + scol * 128 +
                                         (((st * 32 + hi * 8) * 2) ^ ((scol & 7) << 4)));
        s4[nf] = __builtin_amdgcn_mfma_f32_16x16x32_bf16(qf[st], kf, s4[nf], 0, 0, 0);
      }
    }

    // online softmax (wave-parallel: reduce over 16-lane col groups)
    float fr[4];
#pragma unroll
    for (int r = 0; r < 4; ++r) {
      float mx = fmaxf(fmaxf(s4[0][r], s4[1][r]), fmaxf(s4[2][r], s4[3][r]));
#pragma unroll
      for (int msk = 1; msk < 16; msk <<= 1) mx = fmaxf(mx, __shfl_xor(mx, msk, 64));
      const float mnew = fmaxf(mrun[r], mx * SCALE);
      fr[r] = __expf(mrun[r] - mnew);
      float rs = 0.f;
#pragma unroll
      for (int nf = 0; nf < 4; ++nf) {
        const float p = __expf(s4[nf][r] * SCALE - mnew);
        s4[nf][r] = p;
        rs += p;
      }
#pragma unroll
      for (int msk = 1; msk < 16; msk <<= 1) rs += __shfl_xor(rs, msk, 64);
      lrun[r] = lrun[r] * fr[r] + rs;
      mrun[r] = mnew;
    }
#pragma unroll
    for (int nf = 0; nf < 4; ++nf)
#pragma unroll
      for (int r = 0; r < 4; ++r) o[nf][r] *= fr[r];

    // redistribute P (C-layout) -> A-fragment layout via per-wave LDS bounce
#pragma unroll
    for (int nf = 0; nf < 4; ++nf)
#pragma unroll
      for (int r = 0; r < 4; ++r) {
        const int k = nf * 16 + l15;
        const int st = k >> 5, kk = k & 31;
        Pf[wid * 1024 + st * 512 + ((kk >> 3) * 16 + hi * 4 + r) * 8 + (kk & 7)] = f2bf(s4[nf][r]);
      }
    asm volatile("s_waitcnt lgkmcnt(0)" ::: "memory");
    short8_t pa0 = *(const short8_t*)&Pf[wid * 1024 + lane * 8];
    short8_t pa1 = *(const short8_t*)&Pf[wid * 1024 + 512 + lane * 8];

    // PV: o[16 x 64] += P[16 x 64] * V[64 x 64]
#pragma unroll
    for (int nf = 0; nf < 4; ++nf) {
      const int d = nf * 16 + l15;
#pragma unroll
      for (int st = 0; st < 2; ++st) {
        short8_t vf = *(const short8_t*)((const char*)Vt + d * 128 +
                                         (((st * 32 + hi * 8) * 2) ^ ((d & 7) << 4)));
        o[nf] = __builtin_amdgcn_mfma_f32_16x16x32_bf16(st == 0 ? pa0 : pa1, vf, o[nf], 0, 0, 0);
      }
    }
  }

  const int b = bh >> 4, h = bh & 15;
#pragma unroll
  for (int nf = 0; nf < 4; ++nf)
#pragma unroll
    for (int r = 0; r < 4; ++r) {
      const int s = q0 + wid * 16 + hi * 4 + r;
      ctx[(b * S + s) * H + h * 64 + nf * 16 + l15] = f2bf(o[nf][r] / lrun[r]);
    }
}

// ---------------- output GEMM + bias (fp32 out) ----------------
__global__ __launch_bounds__(256, 2)
void gemm_out(const short* __restrict__ A, const short* __restrict__ Wt,
              const float* __restrict__ bias, float* __restrict__ out) {
  __shared__ __align__(16) short As[128 * 32];
  __shared__ __align__(16) short Bs[128 * 32];
  const int tid = threadIdx.x, lane = tid & 63, wid = tid >> 6;
  const int l15 = lane & 15, hi = lane >> 4;
  const int m0 = blockIdx.x * 128, n0 = blockIdx.y * 128;
  const int wr = wid >> 1, wc = wid & 1;
  f32x4 acc[4][4];
#pragma unroll
  for (int m = 0; m < 4; ++m)
#pragma unroll
    for (int n = 0; n < 4; ++n) acc[m][n] = (f32x4){0.f, 0.f, 0.f, 0.f};

  for (int kt = 0; kt < 32; ++kt) {
    const int k0 = kt * 32;
    __syncthreads();
#pragma unroll
    for (int j = 0; j < 2; ++j) {
      const int c = j * 256 + wid * 64 + lane;
      glds16(A + (m0 + (c >> 2)) * 1024 + k0 + (c & 3) * 8,
             (char*)As + (j * 256 + wid * 64) * 16);
      glds16(Wt + (n0 + (c >> 2)) * 1024 + k0 + (c & 3) * 8,
             (char*)Bs + (j * 256 + wid * 64) * 16);
    }
    __syncthreads();
    short8_t a[4], b[4];
#pragma unroll
    for (int m = 0; m < 4; ++m)
      a[m] = *(const short8_t*)&As[(wr * 64 + m * 16 + l15) * 32 + hi * 8];
#pragma unroll
    for (int n = 0; n < 4; ++n)
      b[n] = *(const short8_t*)&Bs[(wc * 64 + n * 16 + l15) * 32 + hi * 8];
#pragma unroll
    for (int m = 0; m < 4; ++m)
#pragma unroll
      for (int n = 0; n < 4; ++n)
        acc[m][n] = __builtin_amdgcn_mfma_f32_16x16x32_bf16(a[m], b[n], acc[m][n], 0, 0, 0);
  }

#pragma unroll
  for (int m = 0; m < 4; ++m)
#pragma unroll
    for (int r = 0; r < 4; ++r) {
      const int grow = m0 + wr * 64 + m * 16 + hi * 4 + r;
#pragma unroll
      for (int n = 0; n < 4; ++n) {
        const int gcol = n0 + wc * 64 + n * 16 + l15;
        out[grow * 1024 + gcol] = acc[m][n][r] + bias[gcol];
      }
    }
}

}  // namespace

extern "C" void kernel_launch(void* const* d_in, const int* in_sizes, int n_in,
                              void* d_out, int out_size, void* d_ws, size_t ws_size,
                              hipStream_t stream) {
  const int* positions = (const int*)d_in[0];
  const float* hidden = (const float*)d_in[1];
  const float* Wqkv = (const float*)d_in[2];
  const float* bqkv = (const float*)d_in[3];
  const float* Wout = (const float*)d_in[4];
  const float* bout = (const float*)d_in[5];
  float* out = (float*)d_out;
  char* ws = (char*)d_ws;

  // workspace layout (bytes); Cb aliases Xb (X dead after gemm_qkv)
  short* Xb  = (short*)(ws + 0);         // 16 MiB  [8192][1024] bf16
  short* Wb  = (short*)(ws + 16777216);  // 6 MiB   [3072][1024] bf16 (W^T)
  short* Wob = (short*)(ws + 23068672);  // 2 MiB   [1024][1024] bf16 (W^T)
  short* Qb  = (short*)(ws + 25165824);  // 16 MiB  [64][2048][64] bf16
  short* Kb  = (short*)(ws + 41943040);  // 16 MiB
  short* Vb  = (short*)(ws + 58720256);  // 16 MiB
  float* ctab = (float*)(ws + 75497472); // 256 KiB [2048][32] f32
  float* stab = (float*)(ws + 75759616); // 256 KiB
  short* Cb  = Xb;                       // ctx reuses X region

  cvt_f32_bf16<<<1024, 256, 0, stream>>>(hidden, Xb, (Bsz * S * H) / 4);
  tconv<<<dim3(NQKV / 32, H / 32), dim3(32, 8), 0, stream>>>(Wqkv, Wb, H, NQKV);
  tconv<<<dim3(H / 32, H / 32), dim3(32, 8), 0, stream>>>(Wout, Wob, H, H);
  rope_tab<<<(S * 32) / 256, 256, 0, stream>>>(positions, ctab, stab);
  gemm_qkv<<<dim3(M / 128, NQKV / 128), 256, 0, stream>>>(Xb, Wb, bqkv, ctab, stab, Qb, Kb, Vb);
  attn<<<dim3(S / 64, Bsz * HH), 256, 0, stream>>>(Qb, Kb, Vb, Cb);
  gemm_out<<<dim3(M / 128, H / 128), 256, 0, stream>>>(Cb, Wob, bout, out);
}

// Round 8
// 404.072 us; speedup vs baseline: 1.2134x; 1.2134x over previous
//
#include <hip/hip_runtime.h>
#include <hip/hip_bf16.h>

namespace {

constexpr int Bsz = 4, S = 2048, H = 1024, HH = 16, DH = 64;
constexpr int M = Bsz * S;      // 8192 rows
constexpr int NQKV = 3 * H;     // 3072
constexpr float SCALE = 0.125f; // Dh^-0.5
// -ln(10000)/32  (inv_freq = exp(d * this))
constexpr float NEG_LOG_BASE_OVER_HALF = -0.2878231366242557f;

typedef float f32x4 __attribute__((ext_vector_type(4)));
typedef short short8_t __attribute__((ext_vector_type(8)));
typedef short short4_t __attribute__((ext_vector_type(4)));

__device__ __forceinline__ void glds16(const void* g, void* l) {
  __builtin_amdgcn_global_load_lds(
      (const __attribute__((address_space(1))) void*)g,
      (__attribute__((address_space(3))) void*)l, 16, 0, 0);
}

__device__ __forceinline__ short f2bf(float f) {
  __hip_bfloat16 h = __float2bfloat16(f);
  return *reinterpret_cast<short*>(&h);
}

// ---------------- conversion kernels ----------------
__global__ void cvt_f32_bf16(const float* __restrict__ src, short* __restrict__ dst, int n4) {
  int i = blockIdx.x * blockDim.x + threadIdx.x;
  const int stride = gridDim.x * blockDim.x;
  const float4* s4 = reinterpret_cast<const float4*>(src);
  short4_t* d4 = reinterpret_cast<short4_t*>(dst);
  for (; i < n4; i += stride) {
    float4 f = s4[i];
    short4_t o;
    o.x = f2bf(f.x); o.y = f2bf(f.y); o.z = f2bf(f.z); o.w = f2bf(f.w);
    d4[i] = o;
  }
}

// dst[c][r] = bf16(src[r][c]); R,C multiples of 32.
__global__ void tconv(const float* __restrict__ src, short* __restrict__ dst, int R, int C) {
  __shared__ float t[32][33];
  const int c0 = blockIdx.x * 32, r0 = blockIdx.y * 32;
  for (int i = threadIdx.y; i < 32; i += 8)
    t[i][threadIdx.x] = src[(r0 + i) * C + c0 + threadIdx.x];
  __syncthreads();
  for (int i = threadIdx.y; i < 32; i += 8)
    dst[(c0 + i) * R + r0 + threadIdx.x] = f2bf(t[threadIdx.x][i]);
}

// RoPE table: ctab/stab[s*32+d] = cos/sin(positions[s] * base^(-d/32)).
__global__ void rope_tab(const int* __restrict__ positions, float* __restrict__ ctab,
                         float* __restrict__ stab) {
  const int i = blockIdx.x * blockDim.x + threadIdx.x;  // [0, S*32)
  const int s = i >> 5, d = i & 31;
  const float ang = (float)positions[s] * expf((float)d * NEG_LOG_BASE_OVER_HALF);
  ctab[i] = cosf(ang);
  stab[i] = sinf(ang);
}

// ---------------- QKV GEMM + bias + RoPE ----------------
// X: [8192][1024] bf16, Wt: [3072][1024] bf16 (transposed).
// Outputs: Q,K as [bh][s][64]; V TRANSPOSED as [bh][d][s] so attn can stage it
// conflict-free (r5 PMC: scalar V-transpose LDS stores were ~16-way bank
// conflicts, 6.7e7/dispatch).
__global__ __launch_bounds__(256, 2)
void gemm_qkv(const short* __restrict__ X, const short* __restrict__ Wt,
              const float* __restrict__ bias, const float* __restrict__ ctab,
              const float* __restrict__ stab,
              short* __restrict__ Qo, short* __restrict__ Ko, short* __restrict__ Vo) {
  __shared__ __align__(16) short As[128 * 32];
  __shared__ __align__(16) short Bs[128 * 32];
  const int tid = threadIdx.x, lane = tid & 63, wid = tid >> 6;
  const int l15 = lane & 15, hi = lane >> 4;
  const int m0 = blockIdx.x * 128, n0 = blockIdx.y * 128;
  const int wr = wid >> 1, wc = wid & 1;
  f32x4 acc[4][4];
#pragma unroll
  for (int m = 0; m < 4; ++m)
#pragma unroll
    for (int n = 0; n < 4; ++n) acc[m][n] = (f32x4){0.f, 0.f, 0.f, 0.f};

  for (int kt = 0; kt < 32; ++kt) {
    const int k0 = kt * 32;
    __syncthreads();
#pragma unroll
    for (int j = 0; j < 2; ++j) {
      const int c = j * 256 + wid * 64 + lane;
      glds16(X + (m0 + (c >> 2)) * 1024 + k0 + (c & 3) * 8,
             (char*)As + (j * 256 + wid * 64) * 16);
      glds16(Wt + (n0 + (c >> 2)) * 1024 + k0 + (c & 3) * 8,
             (char*)Bs + (j * 256 + wid * 64) * 16);
    }
    __syncthreads();
    short8_t a[4], b[4];
#pragma unroll
    for (int m = 0; m < 4; ++m)
      a[m] = *(const short8_t*)&As[(wr * 64 + m * 16 + l15) * 32 + hi * 8];
#pragma unroll
    for (int n = 0; n < 4; ++n)
      b[n] = *(const short8_t*)&Bs[(wc * 64 + n * 16 + l15) * 32 + hi * 8];
#pragma unroll
    for (int m = 0; m < 4; ++m)
#pragma unroll
      for (int n = 0; n < 4; ++n)
        acc[m][n] = __builtin_amdgcn_mfma_f32_16x16x32_bf16(a[m], b[n], acc[m][n], 0, 0, 0);
  }

  // Epilogue. Wave's 64-col span = one head of one section (q/k/v).
  const int colbase = n0 + wc * 64;
  const int sec = colbase >> 10;          // 0=q 1=k 2=v
  const int hh = (colbase & 1023) >> 6;   // head
  if (sec == 2) {
#pragma unroll
    for (int m = 0; m < 4; ++m)
#pragma unroll
      for (int r = 0; r < 4; ++r) {
        const int grow = m0 + wr * 64 + m * 16 + hi * 4 + r;
        const int b = grow >> 11, s = grow & 2047;
#pragma unroll
        for (int n = 0; n < 4; ++n) {
          const int d = n * 16 + l15;
          // transposed store: V^T[bh][d][s]
          Vo[((b * HH + hh) * DH + d) * S + s] = f2bf(acc[m][n][r] + bias[colbase + d]);
        }
      }
  } else {
    short* const outp = (sec == 0) ? Qo : Ko;
#pragma unroll
    for (int m = 0; m < 4; ++m)
#pragma unroll
      for (int r = 0; r < 4; ++r) {
        const int grow = m0 + wr * 64 + m * 16 + hi * 4 + r;
        const int b = grow >> 11, s = grow & 2047;
        const int base = ((b * HH + hh) * S + s) * DH;
#pragma unroll
        for (int n = 0; n < 2; ++n) {  // pair (n, n+2): d and d+32, same lane
          const int d1 = n * 16 + l15;
          const float x1 = acc[m][n][r] + bias[colbase + d1];
          const float x2 = acc[m][n + 2][r] + bias[colbase + d1 + 32];
          const float cs = ctab[s * 32 + d1], sn = stab[s * 32 + d1];
          outp[base + d1] = f2bf(x1 * cs - x2 * sn);
          outp[base + d1 + 32] = f2bf(x2 * cs + x1 * sn);
        }
      }
  }
}

// ---------------- flash attention ----------------
// Q/K: [bh][s][64] bf16, Vt: [bh][d][s] bf16 (pre-transposed).
// ctx out: [b][s][h*64+d] bf16. One block: 64 q-rows, 4 waves x 16 rows.
__global__ __launch_bounds__(256, 2)
void attn(const short* __restrict__ Q, const short* __restrict__ K,
          const short* __restrict__ Vt, short* __restrict__ ctx) {
  __shared__ __align__(16) short Kl[64 * 64];   // [s][d], XOR-swizzled rows
  __shared__ __align__(16) short Vl[64 * 64];   // [d][s-tile], XOR-swizzled rows
  __shared__ __align__(16) short Pf[4 * 1024];  // per-wave P in A-frag layout (sigma-skewed)
  const int tid = threadIdx.x, lane = tid & 63, wid = tid >> 6;
  const int l15 = lane & 15, hi = lane >> 4;
  const int bh = blockIdx.y;
  const int q0 = blockIdx.x * 64;
  const short* Qb = Q + bh * (S * DH);
  const short* Kb = K + bh * (S * DH);
  const short* Vb = Vt + bh * (DH * S);  // rows are d (length S)

  const int qrow = q0 + wid * 16 + l15;
  short8_t qf[2];
  qf[0] = *(const short8_t*)&Qb[qrow * 64 + hi * 8];
  qf[1] = *(const short8_t*)&Qb[qrow * 64 + 32 + hi * 8];

  // sigma-skew for Pf rows: bijective on [0,64); spreads each store instr's
  // 8 active rows across 8 distinct bank-groups (r5 PMC: unskewed was 8-way).
  const int sigl = (lane >> 2) + (lane & 3) * 16;

  f32x4 o[4];
  float mrun[4], lrun[4];
#pragma unroll
  for (int i = 0; i < 4; ++i) { o[i] = (f32x4){0.f, 0.f, 0.f, 0.f}; mrun[i] = -1e30f; lrun[i] = 0.f; }

  for (int kt = 0; kt < 32; ++kt) {
    __syncthreads();
    // stage K: global_load_lds with the swizzle folded into the *global*
    // source address (m173) — byte-identical mechanism to the r5-passing run.
#pragma unroll
    for (int j = 0; j < 2; ++j) {
      const int c = j * 256 + wid * 64 + lane;
      const int row = c >> 3;
      const int swz = ((c & 7) * 16) ^ ((row & 7) << 4);
      glds16((const char*)(Kb + (kt * 64 + row) * 64) + swz,
             (char*)Kl + (j * 256 + wid * 64) * 16);
    }
    // stage V^T: register round-trip (defensive vs r7 crash — avoids the
    // 256KB-span per-lane glds16 gather, the only not-yet-HW-proven mechanism).
    // Source chunk pre-permuted (q = (c&7)^(row&7)), LDS write LINEAR b128:
    // identical final LDS image; 64 lanes x 16B = 32 banks x 2-way = free.
#pragma unroll
    for (int j = 0; j < 2; ++j) {
      const int c = j * 256 + tid;
      const int row = c >> 3;
      const int q = (c & 7) ^ (row & 7);
      short8_t vv = *(const short8_t*)&Vb[row * S + kt * 64 + q * 8];
      *(short8_t*)&Vl[row * 64 + (c & 7) * 8] = vv;
    }
    __syncthreads();

    // QK^T: scores 16(q) x 64(k) per wave
    f32x4 s4[4];
#pragma unroll
    for (int nf = 0; nf < 4; ++nf) {
      s4[nf] = (f32x4){0.f, 0.f, 0.f, 0.f};
      const int scol = nf * 16 + l15;
#pragma unroll
      for (int st = 0; st < 2; ++st) {
        short8_t kf = *(const short8_t*)((const char*)Kl + scol * 128 +
                                         ((st * 64 + hi * 16) ^ ((scol & 7) << 4)));
        s4[nf] = __builtin_amdgcn_mfma_f32_16x16x32_bf16(qf[st], kf, s4[nf], 0, 0, 0);
      }
    }

    // online softmax (wave-parallel: reduce over 16-lane col groups)
    float fr[4];
#pragma unroll
    for (int r = 0; r < 4; ++r) {
      float mx = fmaxf(fmaxf(s4[0][r], s4[1][r]), fmaxf(s4[2][r], s4[3][r]));
#pragma unroll
      for (int msk = 1; msk < 16; msk <<= 1) mx = fmaxf(mx, __shfl_xor(mx, msk, 64));
      const float mnew = fmaxf(mrun[r], mx * SCALE);
      fr[r] = __expf(mrun[r] - mnew);
      float rs = 0.f;
#pragma unroll
      for (int nf = 0; nf < 4; ++nf) {
        const float p = __expf(s4[nf][r] * SCALE - mnew);
        s4[nf][r] = p;
        rs += p;
      }
#pragma unroll
      for (int msk = 1; msk < 16; msk <<= 1) rs += __shfl_xor(rs, msk, 64);
      lrun[r] = lrun[r] * fr[r] + rs;
      mrun[r] = mnew;
    }
#pragma unroll
    for (int nf = 0; nf < 4; ++nf)
#pragma unroll
      for (int r = 0; r < 4; ++r) o[nf][r] *= fr[r];

    // redistribute P (C-layout) -> A-fragment layout via per-wave LDS bounce,
    // rows placed at sigma(ROW) to avoid same-bank-group store collisions.
#pragma unroll
    for (int nf = 0; nf < 4; ++nf)
#pragma unroll
      for (int r = 0; r < 4; ++r) {
        const int k = nf * 16 + l15;
        const int st = k >> 5, kk = k & 31;
        const int ROW = (kk >> 3) * 16 + hi * 4 + r;
        const int sig = (ROW >> 2) + (ROW & 3) * 16;
        Pf[wid * 1024 + st * 512 + sig * 8 + (kk & 7)] = f2bf(s4[nf][r]);
      }
    asm volatile("s_waitcnt lgkmcnt(0)" ::: "memory");
    short8_t pa0 = *(const short8_t*)&Pf[wid * 1024 + sigl * 8];
    short8_t pa1 = *(const short8_t*)&Pf[wid * 1024 + 512 + sigl * 8];

    // PV: o[16 x 64] += P[16 x 64] * V[64 x 64]; V-frags read like K-frags.
#pragma unroll
    for (int nf = 0; nf < 4; ++nf) {
      const int d = nf * 16 + l15;
#pragma unroll
      for (int st = 0; st < 2; ++st) {
        short8_t vf = *(const short8_t*)((const char*)Vl + d * 128 +
                                         ((st * 64 + hi * 16) ^ ((d & 7) << 4)));
        o[nf] = __builtin_amdgcn_mfma_f32_16x16x32_bf16(st == 0 ? pa0 : pa1, vf, o[nf], 0, 0, 0);
      }
    }
  }

  const int b = bh >> 4, h = bh & 15;
#pragma unroll
  for (int nf = 0; nf < 4; ++nf)
#pragma unroll
    for (int r = 0; r < 4; ++r) {
      const int s = q0 + wid * 16 + hi * 4 + r;
      ctx[(b * S + s) * H + h * 64 + nf * 16 + l15] = f2bf(o[nf][r] / lrun[r]);
    }
}

// ---------------- output GEMM + bias (fp32 out) ----------------
__global__ __launch_bounds__(256, 2)
void gemm_out(const short* __restrict__ A, const short* __restrict__ Wt,
              const float* __restrict__ bias, float* __restrict__ out) {
  __shared__ __align__(16) short As[128 * 32];
  __shared__ __align__(16) short Bs[128 * 32];
  const int tid = threadIdx.x, lane = tid & 63, wid = tid >> 6;
  const int l15 = lane & 15, hi = lane >> 4;
  const int m0 = blockIdx.x * 128, n0 = blockIdx.y * 128;
  const int wr = wid >> 1, wc = wid & 1;
  f32x4 acc[4][4];
#pragma unroll
  for (int m = 0; m < 4; ++m)
#pragma unroll
    for (int n = 0; n < 4; ++n) acc[m][n] = (f32x4){0.f, 0.f, 0.f, 0.f};

  for (int kt = 0; kt < 32; ++kt) {
    const int k0 = kt * 32;
    __syncthreads();
#pragma unroll
    for (int j = 0; j < 2; ++j) {
      const int c = j * 256 + wid * 64 + lane;
      glds16(A + (m0 + (c >> 2)) * 1024 + k0 + (c & 3) * 8,
             (char*)As + (j * 256 + wid * 64) * 16);
      glds16(Wt + (n0 + (c >> 2)) * 1024 + k0 + (c & 3) * 8,
             (char*)Bs + (j * 256 + wid * 64) * 16);
    }
    __syncthreads();
    short8_t a[4], b[4];
#pragma unroll
    for (int m = 0; m < 4; ++m)
      a[m] = *(const short8_t*)&As[(wr * 64 + m * 16 + l15) * 32 + hi * 8];
#pragma unroll
    for (int n = 0; n < 4; ++n)
      b[n] = *(const short8_t*)&Bs[(wc * 64 + n * 16 + l15) * 32 + hi * 8];
#pragma unroll
    for (int m = 0; m < 4; ++m)
#pragma unroll
      for (int n = 0; n < 4; ++n)
        acc[m][n] = __builtin_amdgcn_mfma_f32_16x16x32_bf16(a[m], b[n], acc[m][n], 0, 0, 0);
  }

#pragma unroll
  for (int m = 0; m < 4; ++m)
#pragma unroll
    for (int r = 0; r < 4; ++r) {
      const int grow = m0 + wr * 64 + m * 16 + hi * 4 + r;
#pragma unroll
      for (int n = 0; n < 4; ++n) {
        const int gcol = n0 + wc * 64 + n * 16 + l15;
        out[grow * 1024 + gcol] = acc[m][n][r] + bias[gcol];
      }
    }
}

}  // namespace

extern "C" void kernel_launch(void* const* d_in, const int* in_sizes, int n_in,
                              void* d_out, int out_size, void* d_ws, size_t ws_size,
                              hipStream_t stream) {
  const int* positions = (const int*)d_in[0];
  const float* hidden = (const float*)d_in[1];
  const float* Wqkv = (const float*)d_in[2];
  const float* bqkv = (const float*)d_in[3];
  const float* Wout = (const float*)d_in[4];
  const float* bout = (const float*)d_in[5];
  float* out = (float*)d_out;
  char* ws = (char*)d_ws;

  // workspace layout (bytes); Cb aliases Xb (X dead after gemm_qkv)
  short* Xb  = (short*)(ws + 0);         // 16 MiB  [8192][1024] bf16
  short* Wb  = (short*)(ws + 16777216);  // 6 MiB   [3072][1024] bf16 (W^T)
  short* Wob = (short*)(ws + 23068672);  // 2 MiB   [1024][1024] bf16 (W^T)
  short* Qb  = (short*)(ws + 25165824);  // 16 MiB  [64][2048][64] bf16
  short* Kb  = (short*)(ws + 41943040);  // 16 MiB
  short* Vtb = (short*)(ws + 58720256);  // 16 MiB  [64][64][2048] bf16 (V^T)
  float* ctab = (float*)(ws + 75497472); // 256 KiB [2048][32] f32
  float* stab = (float*)(ws + 75759616); // 256 KiB
  short* Cb  = Xb;                       // ctx reuses X region

  cvt_f32_bf16<<<1024, 256, 0, stream>>>(hidden, Xb, (Bsz * S * H) / 4);
  tconv<<<dim3(NQKV / 32, H / 32), dim3(32, 8), 0, stream>>>(Wqkv, Wb, H, NQKV);
  tconv<<<dim3(H / 32, H / 32), dim3(32, 8), 0, stream>>>(Wout, Wob, H, H);
  rope_tab<<<(S * 32) / 256, 256, 0, stream>>>(positions, ctab, stab);
  gemm_qkv<<<dim3(M / 128, NQKV / 128), 256, 0, stream>>>(Xb, Wb, bqkv, ctab, stab, Qb, Kb, Vtb);
  attn<<<dim3(S / 64, Bsz * HH), 256, 0, stream>>>(Qb, Kb, Vtb, Cb);
  gemm_out<<<dim3(M / 128, H / 128), 256, 0, stream>>>(Cb, Wob, bout, out);
}

// Round 11
// 323.689 us; speedup vs baseline: 1.5147x; 1.2483x over previous
//
#include <hip/hip_runtime.h>
#include <hip/hip_bf16.h>

namespace {

constexpr int Bsz = 4, S = 2048, H = 1024, HH = 16, DH = 64;
constexpr int M = Bsz * S;      // 8192 rows
constexpr int NQKV = 3 * H;     // 3072
// -ln(10000)/32  (inv_freq = exp(d * this))
constexpr float NEG_LOG_BASE_OVER_HALF = -0.2878231366242557f;

typedef float f32x4 __attribute__((ext_vector_type(4)));
typedef float f32x16 __attribute__((ext_vector_type(16)));
typedef short short8_t __attribute__((ext_vector_type(8)));
typedef short short4_t __attribute__((ext_vector_type(4)));

union U32x4S8 { uint4 u; short8_t s; };

__device__ __forceinline__ void glds16(const void* g, void* l) {
  __builtin_amdgcn_global_load_lds(
      (const __attribute__((address_space(1))) void*)g,
      (__attribute__((address_space(3))) void*)l, 16, 0, 0);
}

__device__ __forceinline__ short f2bf(float f) {
  __hip_bfloat16 h = __float2bfloat16(f);
  return *reinterpret_cast<short*>(&h);
}

// ---------------- conversion kernels ----------------
__global__ void cvt_f32_bf16(const float* __restrict__ src, short* __restrict__ dst, int n4) {
  int i = blockIdx.x * blockDim.x + threadIdx.x;
  const int stride = gridDim.x * blockDim.x;
  const float4* s4 = reinterpret_cast<const float4*>(src);
  short4_t* d4 = reinterpret_cast<short4_t*>(dst);
  for (; i < n4; i += stride) {
    float4 f = s4[i];
    short4_t o;
    o.x = f2bf(f.x); o.y = f2bf(f.y); o.z = f2bf(f.z); o.w = f2bf(f.w);
    d4[i] = o;
  }
}

// dst[c][r] = bf16(src[r][c]); R,C multiples of 32.
__global__ void tconv(const float* __restrict__ src, short* __restrict__ dst, int R, int C) {
  __shared__ float t[32][33];
  const int c0 = blockIdx.x * 32, r0 = blockIdx.y * 32;
  for (int i = threadIdx.y; i < 32; i += 8)
    t[i][threadIdx.x] = src[(r0 + i) * C + c0 + threadIdx.x];
  __syncthreads();
  for (int i = threadIdx.y; i < 32; i += 8)
    dst[(c0 + i) * R + r0 + threadIdx.x] = f2bf(t[threadIdx.x][i]);
}

// RoPE table: ctab/stab[s*32+d] = cos/sin(positions[s] * base^(-d/32)).
__global__ void rope_tab(const int* __restrict__ positions, float* __restrict__ ctab,
                         float* __restrict__ stab) {
  const int i = blockIdx.x * blockDim.x + threadIdx.x;  // [0, S*32)
  const int s = i >> 5, d = i & 31;
  const float ang = (float)positions[s] * expf((float)d * NEG_LOG_BASE_OVER_HALF);
  ctab[i] = cosf(ang);
  stab[i] = sinf(ang);
}

// ---------------- QKV GEMM + bias + RoPE ----------------
// X: [8192][1024] bf16, Wt: [3072][1024] bf16 (transposed).
// Q is PRE-SCALED by Dh^-0.5 = 0.125 (exact in bf16: exponent shift) so attn's
// softmax skips the scale mul. Q,K: [bh][s][64]; V TRANSPOSED: [bh][d][s].
__global__ __launch_bounds__(256, 2)
void gemm_qkv(const short* __restrict__ X, const short* __restrict__ Wt,
              const float* __restrict__ bias, const float* __restrict__ ctab,
              const float* __restrict__ stab,
              short* __restrict__ Qo, short* __restrict__ Ko, short* __restrict__ Vo) {
  __shared__ __align__(16) short As[128 * 32];
  __shared__ __align__(16) short Bs[128 * 32];
  const int tid = threadIdx.x, lane = tid & 63, wid = tid >> 6;
  const int l15 = lane & 15, hi = lane >> 4;
  const int m0 = blockIdx.x * 128, n0 = blockIdx.y * 128;
  const int wr = wid >> 1, wc = wid & 1;
  f32x4 acc[4][4];
#pragma unroll
  for (int m = 0; m < 4; ++m)
#pragma unroll
    for (int n = 0; n < 4; ++n) acc[m][n] = (f32x4){0.f, 0.f, 0.f, 0.f};

  for (int kt = 0; kt < 32; ++kt) {
    const int k0 = kt * 32;
    __syncthreads();
#pragma unroll
    for (int j = 0; j < 2; ++j) {
      const int c = j * 256 + wid * 64 + lane;
      glds16(X + (m0 + (c >> 2)) * 1024 + k0 + (c & 3) * 8,
             (char*)As + (j * 256 + wid * 64) * 16);
      glds16(Wt + (n0 + (c >> 2)) * 1024 + k0 + (c & 3) * 8,
             (char*)Bs + (j * 256 + wid * 64) * 16);
    }
    __syncthreads();
    short8_t a[4], b[4];
#pragma unroll
    for (int m = 0; m < 4; ++m)
      a[m] = *(const short8_t*)&As[(wr * 64 + m * 16 + l15) * 32 + hi * 8];
#pragma unroll
    for (int n = 0; n < 4; ++n)
      b[n] = *(const short8_t*)&Bs[(wc * 64 + n * 16 + l15) * 32 + hi * 8];
#pragma unroll
    for (int m = 0; m < 4; ++m)
#pragma unroll
      for (int n = 0; n < 4; ++n)
        acc[m][n] = __builtin_amdgcn_mfma_f32_16x16x32_bf16(a[m], b[n], acc[m][n], 0, 0, 0);
  }

  // Epilogue. Wave's 64-col span = one head of one section (q/k/v).
  const int colbase = n0 + wc * 64;
  const int sec = colbase >> 10;          // 0=q 1=k 2=v
  const int hh = (colbase & 1023) >> 6;   // head
  if (sec == 2) {
#pragma unroll
    for (int m = 0; m < 4; ++m)
#pragma unroll
      for (int r = 0; r < 4; ++r) {
        const int grow = m0 + wr * 64 + m * 16 + hi * 4 + r;
        const int b = grow >> 11, s = grow & 2047;
#pragma unroll
        for (int n = 0; n < 4; ++n) {
          const int d = n * 16 + l15;
          // transposed store: V^T[bh][d][s]
          Vo[((b * HH + hh) * DH + d) * S + s] = f2bf(acc[m][n][r] + bias[colbase + d]);
        }
      }
  } else {
    short* const outp = (sec == 0) ? Qo : Ko;
    const float qsc = (sec == 0) ? 0.125f : 1.0f;  // fold Dh^-0.5 into Q (exact)
#pragma unroll
    for (int m = 0; m < 4; ++m)
#pragma unroll
      for (int r = 0; r < 4; ++r) {
        const int grow = m0 + wr * 64 + m * 16 + hi * 4 + r;
        const int b = grow >> 11, s = grow & 2047;
        const int base = ((b * HH + hh) * S + s) * DH;
#pragma unroll
        for (int n = 0; n < 2; ++n) {  // pair (n, n+2): d and d+32, same lane
          const int d1 = n * 16 + l15;
          const float x1 = acc[m][n][r] + bias[colbase + d1];
          const float x2 = acc[m][n + 2][r] + bias[colbase + d1 + 32];
          const float cs = ctab[s * 32 + d1], sn = stab[s * 32 + d1];
          outp[base + d1] = f2bf((x1 * cs - x2 * sn) * qsc);
          outp[base + d1 + 32] = f2bf((x2 * cs + x1 * sn) * qsc);
        }
      }
  }
}

// ---------------- flash attention, swapped-operand 32x32 ----------------
// Q/K: [bh][s][64] bf16 (Q pre-scaled), Vt: [bh][d][s] bf16.
// Block: 4 waves x 32 q-rows = 128 q-rows. Per wave: S^T = K·Q^T via
// mfma_32x32x16 so each lane owns a full half-row of P (16 kv) for ONE q
// (partner lane^32 owns the other 16) -> softmax is in-register + 2 shfl;
// P->PV B-frag is 8 pack + 8 shfl + cndmask (r8 PMC: old layout spent
// 32 shfl + 16 ds_write_b16 per tile on this; MfmaUtil 12%, VALUBusy 42%).
__global__ __launch_bounds__(256, 2)
void attn(const short* __restrict__ Q, const short* __restrict__ K,
          const short* __restrict__ Vt, short* __restrict__ ctx) {
  __shared__ __align__(16) short Kl[64 * 64];   // [kv][d], XOR-swizzled rows
  __shared__ __align__(16) short Vl[64 * 64];   // [d][kv], XOR-swizzled rows
  const int tid = threadIdx.x, lane = tid & 63, wid = tid >> 6;
  const int col = lane & 31, h = lane >> 5;
  const int bh = blockIdx.y;
  const int q0 = blockIdx.x * 128;
  const short* Qb = Q + bh * (S * DH);
  const short* Kb = K + bh * (S * DH);
  const short* Vb = Vt + bh * (DH * S);  // rows are d (length S)

  // Q B-fragments, hoisted: B[k=d][col=q], lane holds Q[q0+wid*32+col][dstep*16+h*8+e]
  const int qrow = q0 + wid * 32 + col;
  short8_t qf[4];
#pragma unroll
  for (int st = 0; st < 4; ++st)
    qf[st] = *(const short8_t*)&Qb[qrow * 64 + st * 16 + h * 8];

  f32x16 o0, o1;
#pragma unroll
  for (int r = 0; r < 16; ++r) { o0[r] = 0.f; o1[r] = 0.f; }
  float mrun = -1e30f, lrun = 0.f;

  for (int kt = 0; kt < 32; ++kt) {
    __syncthreads();
    // stage K: glds16, swizzle folded into global source address (m173)
#pragma unroll
    for (int j = 0; j < 2; ++j) {
      const int c = j * 256 + wid * 64 + lane;
      const int row = c >> 3;
      const int swz = ((c & 7) * 16) ^ ((row & 7) << 4);
      glds16((const char*)(Kb + (kt * 64 + row) * 64) + swz,
             (char*)Kl + (j * 256 + wid * 64) * 16);
    }
    // stage V^T: register round-trip, source chunk pre-permuted, linear b128 write
#pragma unroll
    for (int j = 0; j < 2; ++j) {
      const int c = j * 256 + tid;
      const int row = c >> 3;
      const int q = (c & 7) ^ (row & 7);
      short8_t vv = *(const short8_t*)&Vb[row * S + kt * 64 + q * 8];
      *(short8_t*)&Vl[row * 64 + (c & 7) * 8] = vv;
    }
    __syncthreads();

#pragma unroll
    for (int sub = 0; sub < 2; ++sub) {
      const int kv = sub * 32 + col;
      // S^T[kv][q]: A = K rows kv, B = Q^T; C col=q(lane&31), row=kv slice in-lane
      f32x16 s;
#pragma unroll
      for (int r = 0; r < 16; ++r) s[r] = 0.f;
#pragma unroll
      for (int dstep = 0; dstep < 4; ++dstep) {
        short8_t af = *(const short8_t*)((const char*)Kl + kv * 128 +
                                         ((dstep * 32 + h * 16) ^ ((kv & 7) << 4)));
        s = __builtin_amdgcn_mfma_f32_32x32x16_bf16(af, qf[dstep], s, 0, 0, 0);
      }
      // online softmax: all 16 in-lane values share q=col; partner lane^32 has other 16 kv
      float smax = s[0];
#pragma unroll
      for (int r = 1; r < 16; ++r) smax = fmaxf(smax, s[r]);
      smax = fmaxf(smax, __shfl_xor(smax, 32, 64));
      const float mnew = fmaxf(mrun, smax);
      const float fr = __expf(mrun - mnew);
      float p[16];
      float rs = 0.f;
#pragma unroll
      for (int r = 0; r < 16; ++r) { p[r] = __expf(s[r] - mnew); rs += p[r]; }
      rs += __shfl_xor(rs, 32, 64);
      lrun = lrun * fr + rs;
      mrun = mnew;
#pragma unroll
      for (int r = 0; r < 16; ++r) { o0[r] *= fr; o1[r] *= fr; }

      // P -> PV B-frags in-register. Lane(h) word j = kv pair {(j&1)*2 + 8*(j>>1)... }:
      // j: regs(2j,2j+1) -> kv = 4h + {0,1}/{2,3} + 8*(j>>1 pattern); partner via shfl^32.
      uint w[8], sw[8];
#pragma unroll
      for (int j = 0; j < 8; ++j)
        w[j] = (uint)(ushort)f2bf(p[2 * j]) | ((uint)(ushort)f2bf(p[2 * j + 1]) << 16);
#pragma unroll
      for (int j = 0; j < 8; ++j)
        sw[j] = (uint)__shfl_xor((int)w[j], 32, 64);
      // b0: kv sub*32 + h*8 + {0..7} ; b1: kv sub*32 + 16 + h*8 + {0..7}
      U32x4S8 b0, b1;
      b0.u.x = h ? sw[2] : w[0];  b0.u.y = h ? sw[3] : w[1];
      b0.u.z = h ? w[2] : sw[0];  b0.u.w = h ? w[3] : sw[1];
      b1.u.x = h ? sw[6] : w[4];  b1.u.y = h ? sw[7] : w[5];
      b1.u.z = h ? w[6] : sw[4];  b1.u.w = h ? w[7] : sw[5];

      // PV: O^T[d][q] += V^T[d][kv] · P^T[kv][q]; A from Vl (rows d), B = b0/b1
#pragma unroll
      for (int st2 = 0; st2 < 2; ++st2) {
        const short8_t pb = st2 ? b1.s : b0.s;
        const int cb = (sub * 64 + st2 * 32 + h * 16) ^ ((col & 7) << 4);
        short8_t vf0 = *(const short8_t*)((const char*)Vl + col * 128 + cb);
        o0 = __builtin_amdgcn_mfma_f32_32x32x16_bf16(vf0, pb, o0, 0, 0, 0);
        short8_t vf1 = *(const short8_t*)((const char*)Vl + (32 + col) * 128 + cb);
        o1 = __builtin_amdgcn_mfma_f32_32x32x16_bf16(vf1, pb, o1, 0, 0, 0);
      }
    }
  }

  // epilogue: O[q][d] = O^T[d][q] / l ; d = db*32 + (r&3) + 8*(r>>2) + 4h
  const float inv = 1.0f / lrun;
  const int b = bh >> 4, hh = bh & 15;
  const long obase = (long)(b * S + qrow) * H + hh * 64;
#pragma unroll
  for (int r = 0; r < 16; ++r) {
    const int d = (r & 3) + 8 * (r >> 2) + 4 * h;
    ctx[obase + d] = f2bf(o0[r] * inv);
    ctx[obase + 32 + d] = f2bf(o1[r] * inv);
  }
}

// ---------------- output GEMM + bias (fp32 out) ----------------
__global__ __launch_bounds__(256, 2)
void gemm_out(const short* __restrict__ A, const short* __restrict__ Wt,
              const float* __restrict__ bias, float* __restrict__ out) {
  __shared__ __align__(16) short As[128 * 32];
  __shared__ __align__(16) short Bs[128 * 32];
  const int tid = threadIdx.x, lane = tid & 63, wid = tid >> 6;
  const int l15 = lane & 15, hi = lane >> 4;
  const int m0 = blockIdx.x * 128, n0 = blockIdx.y * 128;
  const int wr = wid >> 1, wc = wid & 1;
  f32x4 acc[4][4];
#pragma unroll
  for (int m = 0; m < 4; ++m)
#pragma unroll
    for (int n = 0; n < 4; ++n) acc[m][n] = (f32x4){0.f, 0.f, 0.f, 0.f};

  for (int kt = 0; kt < 32; ++kt) {
    const int k0 = kt * 32;
    __syncthreads();
#pragma unroll
    for (int j = 0; j < 2; ++j) {
      const int c = j * 256 + wid * 64 + lane;
      glds16(A + (m0 + (c >> 2)) * 1024 + k0 + (c & 3) * 8,
             (char*)As + (j * 256 + wid * 64) * 16);
      glds16(Wt + (n0 + (c >> 2)) * 1024 + k0 + (c & 3) * 8,
             (char*)Bs + (j * 256 + wid * 64) * 16);
    }
    __syncthreads();
    short8_t a[4], b[4];
#pragma unroll
    for (int m = 0; m < 4; ++m)
      a[m] = *(const short8_t*)&As[(wr * 64 + m * 16 + l15) * 32 + hi * 8];
#pragma unroll
    for (int n = 0; n < 4; ++n)
      b[n] = *(const short8_t*)&Bs[(wc * 64 + n * 16 + l15) * 32 + hi * 8];
#pragma unroll
    for (int m = 0; m < 4; ++m)
#pragma unroll
      for (int n = 0; n < 4; ++n)
        acc[m][n] = __builtin_amdgcn_mfma_f32_16x16x32_bf16(a[m], b[n], acc[m][n], 0, 0, 0);
  }

#pragma unroll
  for (int m = 0; m < 4; ++m)
#pragma unroll
    for (int r = 0; r < 4; ++r) {
      const int grow = m0 + wr * 64 + m * 16 + hi * 4 + r;
#pragma unroll
      for (int n = 0; n < 4; ++n) {
        const int gcol = n0 + wc * 64 + n * 16 + l15;
        out[grow * 1024 + gcol] = acc[m][n][r] + bias[gcol];
      }
    }
}

}  // namespace

extern "C" void kernel_launch(void* const* d_in, const int* in_sizes, int n_in,
                              void* d_out, int out_size, void* d_ws, size_t ws_size,
                              hipStream_t stream) {
  const int* positions = (const int*)d_in[0];
  const float* hidden = (const float*)d_in[1];
  const float* Wqkv = (const float*)d_in[2];
  const float* bqkv = (const float*)d_in[3];
  const float* Wout = (const float*)d_in[4];
  const float* bout = (const float*)d_in[5];
  float* out = (float*)d_out;
  char* ws = (char*)d_ws;

  // workspace layout (bytes); Cb aliases Xb (X dead after gemm_qkv)
  short* Xb  = (short*)(ws + 0);         // 16 MiB  [8192][1024] bf16
  short* Wb  = (short*)(ws + 16777216);  // 6 MiB   [3072][1024] bf16 (W^T)
  short* Wob = (short*)(ws + 23068672);  // 2 MiB   [1024][1024] bf16 (W^T)
  short* Qb  = (short*)(ws + 25165824);  // 16 MiB  [64][2048][64] bf16 (pre-scaled)
  short* Kb  = (short*)(ws + 41943040);  // 16 MiB
  short* Vtb = (short*)(ws + 58720256);  // 16 MiB  [64][64][2048] bf16 (V^T)
  float* ctab = (float*)(ws + 75497472); // 256 KiB [2048][32] f32
  float* stab = (float*)(ws + 75759616); // 256 KiB
  short* Cb  = Xb;                       // ctx reuses X region

  cvt_f32_bf16<<<1024, 256, 0, stream>>>(hidden, Xb, (Bsz * S * H) / 4);
  tconv<<<dim3(NQKV / 32, H / 32), dim3(32, 8), 0, stream>>>(Wqkv, Wb, H, NQKV);
  tconv<<<dim3(H / 32, H / 32), dim3(32, 8), 0, stream>>>(Wout, Wob, H, H);
  rope_tab<<<(S * 32) / 256, 256, 0, stream>>>(positions, ctab, stab);
  gemm_qkv<<<dim3(M / 128, NQKV / 128), 256, 0, stream>>>(Xb, Wb, bqkv, ctab, stab, Qb, Kb, Vtb);
  attn<<<dim3(S / 128, Bsz * HH), 256, 0, stream>>>(Qb, Kb, Vtb, Cb);
  gemm_out<<<dim3(M / 128, H / 128), 256, 0, stream>>>(Cb, Wob, bout, out);
}